// Round 8
// baseline (1376.085 us; speedup 1.0000x reference)
//
#include <hip/hip_runtime.h>
#include <hip/hip_bf16.h>
#include <hip/hip_fp16.h>

// LSTM, T=64. Structure:
//   prep_w : Wx[2048][512], Wh[2048][512] bf16 (gate-interleaved n=4h+g, K-transposed), biasr.
//            Also zeroes the 1024 per-(step,m-group) barrier counters.
//   prep_x : Xbf[t][b][512] bf16 (time-major).
//   zx_gemm: zx[t][b][2048] = Xbf @ Wx^T, fp16 storage (parallel, off the critical path).
//   lstm_persist v4: 256 blocks = 16 m-groups (64 batch rows) x 16 n-slices (128 gate cols),
//            1 block/CU (148 KB dynamic LDS), 64 steps, per-m-group barriers (16 blocks).
//            Wh n-slice LDS-RESIDENT for all 64 steps. Swapped-operand MFMA: D[n][b] =
//            Wh_frag x h_frag -> lane holds (zi,zf,zg,zo) for one (h,b); in-register epilogue.
//            h-exchange v4: BLOCK-TILED stage layout Hstage[buf][nb 16][b 1024][32 h] bf16.
//            Writer: each block stores ONE contiguous 4 KB region (thread tid -> bytes
//            tid*16..+16) = full-64B-line sc0+sc1 write-through, no partial-line RMW
//            (R7's WRITE_SIZE amplification + slow vmcnt drain). Reader: 16 contiguous
//            4 KB regions; every 4-lane group covers a full line. Same XOR-swizzled As.
//            c-state register-resident. No cache-wide fences anywhere.
// LDS swizzle: phys granule = (seg&8)|((seg^row)&7) so unpadded frag reads are bank-optimal.

typedef __attribute__((ext_vector_type(8))) short bfrag8;
typedef __attribute__((ext_vector_type(4))) float facc4;
typedef __attribute__((ext_vector_type(4))) unsigned int u32x4;  // asm-friendly 128b

#define MFMA_B16(a, b, c) __builtin_amdgcn_mfma_f32_16x16x32_bf16(a, b, c, 0, 0, 0)

#define GRP 16u   // blocks per m-group barrier

__device__ __forceinline__ unsigned short f2bf(float f) {
  unsigned int u = __float_as_uint(f);
  u += 0x7FFFu + ((u >> 16) & 1u);          // RNE
  return (unsigned short)(u >> 16);
}
__device__ __forceinline__ float sigm(float x)  { return 1.0f / (1.0f + __expf(-x)); }
__device__ __forceinline__ float tanh_(float x) { return 1.0f - 2.0f / (__expf(2.0f * x) + 1.0f); }

__device__ __forceinline__ void gl2lds16(const void* g, void* l) {
  __builtin_amdgcn_global_load_lds(
      (const __attribute__((address_space(1))) unsigned int*)g,
      (__attribute__((address_space(3))) unsigned int*)l, 16, 0, 0);
}

// Coherent 16B load/store (bypass stale L1/L2, device-coherent point).
// NOTE: asm operands must be ext_vector types (struct uint4 inputs are rejected).
__device__ __forceinline__ u32x4 ld128_coh(const void* p) {
  u32x4 r;
  asm volatile("global_load_dwordx4 %0, %1, off sc0 sc1" : "=v"(r) : "v"(p));
  return r;
}
__device__ __forceinline__ void st128_coh(void* p, u32x4 v) {
  asm volatile("global_store_dwordx4 %0, %1, off sc0 sc1" :: "v"(p), "v"(v));
}

// ushort offset of logical granule (row, seg) in a [rows][16 segs] swizzled tile.
__device__ __forceinline__ int foff(int row, int seg) {
  return (row << 7) + ((((seg & 8) | ((seg ^ row) & 7))) << 3);
}

// Per-m-group barrier (16 blocks), one counter slot per (step, group). No fences:
// h traffic is coherent by construction (sc0 sc1); vmcnt(0) = own stores at coherent point.
__device__ __forceinline__ void group_barrier(unsigned int* bar, int slot) {
  asm volatile("s_waitcnt vmcnt(0)" ::: "memory");   // own h-stores visible device-wide
  __syncthreads();                                   // whole block done with step
  if (threadIdx.x == 0) {
    __hip_atomic_fetch_add(&bar[slot], 1u, __ATOMIC_RELAXED, __HIP_MEMORY_SCOPE_AGENT);
    while (__hip_atomic_load(&bar[slot], __ATOMIC_RELAXED, __HIP_MEMORY_SCOPE_AGENT) < GRP)
      __builtin_amdgcn_s_sleep(2);
  }
  __syncthreads();
}

// ---------------- prep kernels ----------------

__global__ void prep_w(const float* __restrict__ Wk, const float* __restrict__ Wr,
                       const float* __restrict__ bias,
                       unsigned short* __restrict__ Wx, unsigned short* __restrict__ Wh,
                       float* __restrict__ biasr, unsigned int* __restrict__ bar)
{
  int gid = (blockIdx.x << 8) + threadIdx.x;   // 0 .. 2M-1
  int k   = gid >> 11;                         // 0..1023
  int col = gid & 2047;                        // original column g*512+h
  float v = (k < 512) ? Wk[((size_t)k << 11) + col]
                      : Wr[((size_t)(k - 512) << 11) + col];
  int n = ((col & 511) << 2) | (col >> 9);     // 4h+g
  if (k < 512) Wx[((size_t)n << 9) + k]         = f2bf(v);
  else         Wh[((size_t)n << 9) + (k - 512)] = f2bf(v);
  if (gid < 2048) biasr[((gid & 511) << 2) | (gid >> 9)] = bias[gid];
  if (gid < 1024) bar[gid] = 0u;               // zero barrier counters each run
}

__global__ void prep_x(const float* __restrict__ x, unsigned short* __restrict__ Xbf)
{
  int flat = (blockIdx.x << 8) + threadIdx.x;  // 0 .. 4,194,303 (granules of 8)
  int d8 = flat & 63;
  int b  = (flat >> 6) & 1023;
  int t  = flat >> 16;
  const float* src = x + ((((size_t)b << 6) + t) << 9) + (d8 << 3);
  float4 v0 = *(const float4*)src;
  float4 v1 = *(const float4*)(src + 4);
  uint4 u;
  u.x = f2bf(v0.x) | ((unsigned)f2bf(v0.y) << 16);
  u.y = f2bf(v0.z) | ((unsigned)f2bf(v0.w) << 16);
  u.z = f2bf(v1.x) | ((unsigned)f2bf(v1.y) << 16);
  u.w = f2bf(v1.z) | ((unsigned)f2bf(v1.w) << 16);
  *(uint4*)&Xbf[((((size_t)t << 10) + b) << 9) + (d8 << 3)] = u;
}

// ---------------- zx precompute GEMM ----------------
// zx[t][b][n] (fp16) = Xbf[t][b][:] . Wx[n][:]   M=65536, N=2048, K=512
__global__ __launch_bounds__(256, 3)
void zx_gemm(const unsigned short* __restrict__ Xbf, const unsigned short* __restrict__ Wx,
             unsigned short* __restrict__ zx)
{
  __shared__ __align__(16) unsigned short As[8192];   // 16 KB, 1024 granules (swizzled)
  __shared__ __align__(16) unsigned short Bs[8192];
  __shared__ float Zs[64][68];

  const int tid  = threadIdx.x;
  const int lane = tid & 63;
  const int w    = tid >> 6;
  const int llo  = lane & 15;
  const int lhi  = lane >> 4;
  const int wm   = (w >> 1) & 1;
  const int wn   = w & 1;

  const int n0 = blockIdx.x << 6;              // 0..2047 step 64
  const int by = blockIdx.y;                   // 0..1023
  const int t  = by >> 4;
  const int b0 = (by & 15) << 6;

  facc4 acc00 = {0.f,0.f,0.f,0.f};
  facc4 acc01 = acc00, acc10 = acc00, acc11 = acc00;

  const int am0 = (wm << 5) + llo;
  const int bn0 = (wn << 5) + llo;

  for (int ci = 0; ci < 4; ++ci) {
    const int kb = ci << 7;
#pragma unroll
    for (int j = 0; j < 4; ++j) {
      int p = (j << 8) + tid;
      int r = p >> 4, ps = p & 15;
      int s = (ps & 8) | ((ps ^ r) & 7);
      gl2lds16(Xbf + ((((size_t)t << 10) + (b0 + r)) << 9) + kb + (s << 3), &As[p << 3]);
      gl2lds16(Wx  + (((size_t)(n0 + r)) << 9) + kb + (s << 3),             &Bs[p << 3]);
    }
    __syncthreads();
#pragma unroll
    for (int kk = 0; kk < 4; ++kk) {
      const int s0 = (kk << 2) + lhi;
      bfrag8 a0 = *(const bfrag8*)&As[foff(am0,      s0)];
      bfrag8 a1 = *(const bfrag8*)&As[foff(am0 + 16, s0)];
      bfrag8 b0 = *(const bfrag8*)&Bs[foff(bn0,      s0)];
      bfrag8 b1 = *(const bfrag8*)&Bs[foff(bn0 + 16, s0)];
      acc00 = MFMA_B16(a0, b0, acc00);
      acc01 = MFMA_B16(a0, b1, acc01);
      acc10 = MFMA_B16(a1, b0, acc10);
      acc11 = MFMA_B16(a1, b1, acc11);
    }
    __syncthreads();
  }

  // spill: C/D layout col=lane&15, row=(lane>>4)*4+reg
#pragma unroll
  for (int rr = 0; rr < 4; ++rr) {
    int rbase = (wm << 5) + (lhi << 2) + rr;
    int cbase = (wn << 5) + llo;
    Zs[rbase][cbase]           = acc00[rr];
    Zs[rbase][cbase + 16]      = acc01[rr];
    Zs[rbase + 16][cbase]      = acc10[rr];
    Zs[rbase + 16][cbase + 16] = acc11[rr];
  }
  __syncthreads();

  const int hs = tid & 15;
  const int rw = tid >> 4;
#pragma unroll
  for (int it = 0; it < 4; ++it) {
    int row = rw + (it << 4);
    float4 z = *(const float4*)&Zs[row][hs << 2];
    ushort4 o;
    o.x = __half_as_ushort(__float2half(z.x));
    o.y = __half_as_ushort(__float2half(z.y));
    o.z = __half_as_ushort(__float2half(z.z));
    o.w = __half_as_ushort(__float2half(z.w));
    *(ushort4*)&zx[((((size_t)t << 10) + (b0 + row)) << 11) + n0 + (hs << 2)] = o;
  }
}

// ---------------- persistent recurrence v4 ----------------
// 256 blocks = 16 mg (64 rows) x 16 nb (128 gate cols = 32 h), 256 thr, 1 block/CU.
// LDS (dynamic 148 KB): Bs = Wh slice [4 chunks][128 n][128 k] swizzled, RESIDENT;
//                       As = h chunk [64 b][128 k] swizzled; Sc = 4 KB h-repack scratch.
// Hstage[buf][nb 16][b 1024][32 h] bf16: block-tiled so coherent stores/loads are
// full-line coalesced (writer: one 4 KB contiguous region/block/step).
__global__ __launch_bounds__(256, 1)
void lstm_persist(unsigned short* __restrict__ Hbuf,      // [2][16][1024][32] bf16 stage
                  const unsigned short* __restrict__ Wh,  // [2048][512] bf16
                  const unsigned short* __restrict__ zx,  // [64][1024][2048] fp16
                  const float* __restrict__ biasr,
                  float* __restrict__ out,                // [1024][64][512]
                  unsigned int* __restrict__ bar)         // [64][16] barrier counters
{
  extern __shared__ __align__(16) char smem_raw[];
  unsigned short* Bs = (unsigned short*)smem_raw;             // 128 KB
  unsigned short* As = (unsigned short*)(smem_raw + 131072);  // 16 KB
  unsigned short* Sc = (unsigned short*)(smem_raw + 147456);  // 4 KB

  const int tid  = threadIdx.x;
  const int lane = tid & 63;
  const int w    = tid >> 6;        // wave 0..3
  const int llo  = lane & 15;
  const int lhi  = lane >> 4;

  const int bx  = blockIdx.x;
  const int nbI = bx & 15;          // n-slice 0..15
  const int mg  = bx >> 4;          // m-group 0..15
  const int m0  = mg << 6;          // batch-row base
  const int n0  = nbI << 7;         // gate-col base (128 cols)
  const int hb  = nbI << 5;         // h base (32 h)

  // ---- prologue: stage resident Wh slice [n0..n0+128) x [0..512) into Bs ----
  for (int i = 0; i < 32; ++i) {
    int p  = (i << 8) + tid;        // 0..8191 granules of 16B
    int ci = p >> 11;               // K-chunk 0..3
    int q  = p & 2047;
    int r  = q >> 4, ps = q & 15;   // n-row 0..127, seg
    int s  = (ps & 8) | ((ps ^ r) & 7);
    gl2lds16(Wh + (((size_t)(n0 + r)) << 9) + (ci << 7) + (s << 3), Bs + ((size_t)p << 3));
  }

  const int nw0 = w << 5;           // wave's n-strip base within 128
  // bias (t-invariant): bb[nt] = biasr[4h .. 4h+3] for h = hb + w*8 + nt*4 + lhi
  float4 bb[2];
  bb[0] = *(const float4*)&biasr[(size_t)(hb + (w << 3) + 0 + lhi) << 2];
  bb[1] = *(const float4*)&biasr[(size_t)(hb + (w << 3) + 4 + lhi) << 2];

  float c[2][4] = {{0.f,0.f,0.f,0.f},{0.f,0.f,0.f,0.f}};

  asm volatile("s_waitcnt vmcnt(0)" ::: "memory");   // Bs staged
  __syncthreads();

  const size_t HSTG = (size_t)16 * 1024 * 32;        // elems per stage buffer (1 MiB)

  for (int t = 0; t < 64; ++t) {
    const unsigned short* zxt = zx + ((size_t)t << 21);

    // zx prefetch (h-independent; hides under barrier drain + spin)
    ushort4 zp[2][4];
#pragma unroll
    for (int nt = 0; nt < 2; ++nt)
#pragma unroll
      for (int bt = 0; bt < 4; ++bt) {
        int b = m0 + (bt << 4) + llo;
        int h = hb + (w << 3) + (nt << 2) + lhi;
        zp[nt][bt] = *(const ushort4*)&zxt[((size_t)b << 11) + (h << 2)];
      }

    if (t) group_barrier(bar, ((t - 1) << 4) + mg);   // group finished step t-1

    facc4 acc[2][4];
#pragma unroll
    for (int nt = 0; nt < 2; ++nt)
#pragma unroll
      for (int bt = 0; bt < 4; ++bt)
        acc[nt][bt] = (facc4){0.f, 0.f, 0.f, 0.f};

    if (t) {
      const unsigned short* Hs = Hbuf + (size_t)(t & 1) * HSTG;   // stage buf for h_{t-1}
      // single-shot coherent h load: 16 x dwordx4 (64 KB/block), counted vmcnt.
      // Logical granule (row r, k-seg s) lives at Hstage[nb'=4ci+(s>>2)][m0+r][(s&3)*8]
      // -> every 4-lane group covers one full 64B line.
      u32x4 av[16];
#pragma unroll
      for (int ci = 0; ci < 4; ++ci)
#pragma unroll
        for (int j = 0; j < 4; ++j) {
          int p = (j << 8) + tid;
          int r = p >> 4, ps = p & 15;
          int s = (ps & 8) | ((ps ^ r) & 7);
          int nbp = (ci << 2) + (s >> 2);
          av[(ci << 2) + j] =
              ld128_coh(Hs + ((size_t)nbp << 15) + ((size_t)(m0 + r) << 5) + ((s & 3) << 3));
        }
#pragma unroll
      for (int ci = 0; ci < 4; ++ci) {
        if      (ci == 0) asm volatile("s_waitcnt vmcnt(12)" ::: "memory");
        else if (ci == 1) asm volatile("s_waitcnt vmcnt(8)"  ::: "memory");
        else if (ci == 2) asm volatile("s_waitcnt vmcnt(4)"  ::: "memory");
        else              asm volatile("s_waitcnt vmcnt(0)"  ::: "memory");
        __builtin_amdgcn_sched_barrier(0);
#pragma unroll
        for (int j = 0; j < 4; ++j) {
          int p = (j << 8) + tid;
          *(u32x4*)&As[(size_t)p << 3] = av[(ci << 2) + j];
        }
        __syncthreads();
#pragma unroll
        for (int kk = 0; kk < 4; ++kk) {
          const int s0 = (kk << 2) + lhi;
          bfrag8 wh0 = *(const bfrag8*)&Bs[(ci << 14) + foff(nw0 + llo,      s0)];
          bfrag8 wh1 = *(const bfrag8*)&Bs[(ci << 14) + foff(nw0 + 16 + llo, s0)];
#pragma unroll
          for (int bt = 0; bt < 4; ++bt) {
            bfrag8 hf = *(const bfrag8*)&As[foff((bt << 4) + llo, s0)];
            acc[0][bt] = MFMA_B16(wh0, hf, acc[0][bt]);
            acc[1][bt] = MFMA_B16(wh1, hf, acc[1][bt]);
          }
        }
        __syncthreads();
      }
    }

    // ---- in-register epilogue: lane holds (zi,zf,zg,zo) for (h,b) ----
#pragma unroll
    for (int nt = 0; nt < 2; ++nt)
#pragma unroll
      for (int bt = 0; bt < 4; ++bt) {
        int b = m0 + (bt << 4) + llo;
        int h = hb + (w << 3) + (nt << 2) + lhi;
        float zi = acc[nt][bt][0] + __half2float(__ushort_as_half(zp[nt][bt].x)) + bb[nt].x;
        float zf = acc[nt][bt][1] + __half2float(__ushort_as_half(zp[nt][bt].y)) + bb[nt].y;
        float zg = acc[nt][bt][2] + __half2float(__ushort_as_half(zp[nt][bt].z)) + bb[nt].z;
        float zo = acc[nt][bt][3] + __half2float(__ushort_as_half(zp[nt][bt].w)) + bb[nt].w;
        float ig = sigm(zi);
        float fg = sigm(zf);
        float gg = tanh_(zg);
        float og = sigm(zo);
        float cn = fg * c[nt][bt] + ig * gg;
        c[nt][bt] = cn;
        float hn = og * tanh_(cn);
        // repack h via LDS scratch: Sc[wave][64 rows][8 h-of-wave]
        Sc[(w << 9) + (((bt << 4) + llo) << 3) + (nt << 2) + lhi] = f2bf(hn);
        out[((size_t)b << 15) + ((size_t)t << 9) + h] = hn;
      }
    __syncthreads();   // Sc reader crosses wave regions
    {
      // block's 4 KB stage region written fully-coalesced: thread tid -> bytes tid*16..+16
      // (row = tid>>2, col-granule = tid&3 reads Sc[wave=tid&3][row][0..8])
      u32x4 hv = *(const u32x4*)&Sc[((tid & 3) << 9) + ((tid >> 2) << 3)];
      unsigned short* Hn = Hbuf + (size_t)((t + 1) & 1) * HSTG;
      st128_coh(Hn + ((size_t)nbI << 15) + ((size_t)(m0 + (tid >> 2)) << 5) + ((tid & 3) << 3), hv);
    }
    // As/Sc reuse hazard vs next step covered by group_barrier's __syncthreads.
  }
}

extern "C" void kernel_launch(void* const* d_in, const int* in_sizes, int n_in,
                              void* d_out, int out_size, void* d_ws, size_t ws_size,
                              hipStream_t stream) {
  const float* x    = (const float*)d_in[0];   // [1024][64][512]
  const float* Wk   = (const float*)d_in[1];   // [512][2048]
  const float* Wr   = (const float*)d_in[2];   // [512][2048]
  const float* bias = (const float*)d_in[3];   // [2048]
  float* out = (float*)d_out;                  // [1024][64][512]

  char* ws = (char*)d_ws;
  // ws (16B-aligned): Wx 2MiB | Wh 2MiB | biasr 8KB | Hbuf 2x1MiB | bar 4KB | Xbf 64MiB | zx 256MiB
  unsigned short* Wx    = (unsigned short*)(ws);
  unsigned short* Wh    = (unsigned short*)(ws + (2u << 20));
  float*          biasr = (float*)(ws + (4u << 20));
  unsigned short* Hbuf  = (unsigned short*)(ws + (4u << 20) + 8192);
  unsigned int*   bar   = (unsigned int*)(ws + (6u << 20) + 8192);
  unsigned short* Xbf   = (unsigned short*)(ws + (8u << 20) + 8192);
  unsigned short* zx    = (unsigned short*)(ws + (72u << 20) + 8192);

  (void)hipFuncSetAttribute((const void*)lstm_persist,
                            hipFuncAttributeMaxDynamicSharedMemorySize, 151552);

  prep_w<<<dim3(8192), dim3(256), 0, stream>>>(Wk, Wr, bias, Wx, Wh, biasr, bar);
  prep_x<<<dim3(16384), dim3(256), 0, stream>>>(x, Xbf);
  zx_gemm<<<dim3(32, 1024), dim3(256), 0, stream>>>(Xbf, Wx, zx);
  lstm_persist<<<dim3(256), dim3(256), 151552, stream>>>(Hbuf, Wh, zx, biasr, out, bar);
}

// Round 9
// 1163.576 us; speedup vs baseline: 1.1826x; 1.1826x over previous
//
#include <hip/hip_runtime.h>
#include <hip/hip_bf16.h>
#include <hip/hip_fp16.h>

// LSTM, T=64. Structure:
//   prep_w : Wx[2048][512], Wh[2048][512] bf16 (gate-interleaved n=4h+g, K-transposed), biasr.
//            Also zeroes the 4096 producer counters.
//   prep_x : Xbf[t][b][512] bf16 (time-major).
//   zx_gemm: zx[t][b][2048] = Xbf @ Wx^T, fp16 storage (parallel, off the critical path).
//   lstm_persist v5: 256 blocks = 16 m-groups (64 batch rows) x 16 n-slices (128 gate cols),
//            1 block/CU (148 KB dynamic LDS), 64 steps. NO rendezvous barrier: producer-flag
//            dataflow. Producer (mg,nb) at end of step t stores its 4 KB h-slice into a
//            4-DEEP stage ring Hstage[(t+1)&3][nb][1024 b][32 h], drains (counted vmcnt(8):
//            out-stores don't gate), syncs, then cnt[t+1][mg][nb>>2] += 1. Consumer at step
//            t: threads 0-3 poll the 4 chunk-counters concurrently (==4 each), one sync,
//            then the existing single-shot 16x dwordx4 coherent load + counted-vmcnt
//            LDS/MFMA pipeline. Max inter-block drift = 1 step -> mod-4 ring is race-free,
//            no reverse-wait. Wh n-slice LDS-RESIDENT; swapped-operand MFMA (lane holds
//            zi,zf,zg,zo for one (h,b)); in-register epilogue; c in registers.
// LDS swizzle: phys granule = (seg&8)|((seg^row)&7) so unpadded frag reads are bank-optimal.

typedef __attribute__((ext_vector_type(8))) short bfrag8;
typedef __attribute__((ext_vector_type(4))) float facc4;
typedef __attribute__((ext_vector_type(4))) unsigned int u32x4;  // asm-friendly 128b

#define MFMA_B16(a, b, c) __builtin_amdgcn_mfma_f32_16x16x32_bf16(a, b, c, 0, 0, 0)

__device__ __forceinline__ unsigned short f2bf(float f) {
  unsigned int u = __float_as_uint(f);
  u += 0x7FFFu + ((u >> 16) & 1u);          // RNE
  return (unsigned short)(u >> 16);
}
__device__ __forceinline__ float sigm(float x)  { return 1.0f / (1.0f + __expf(-x)); }
__device__ __forceinline__ float tanh_(float x) { return 1.0f - 2.0f / (__expf(2.0f * x) + 1.0f); }

__device__ __forceinline__ void gl2lds16(const void* g, void* l) {
  __builtin_amdgcn_global_load_lds(
      (const __attribute__((address_space(1))) unsigned int*)g,
      (__attribute__((address_space(3))) unsigned int*)l, 16, 0, 0);
}

// Coherent 16B load/store (bypass stale L1/L2, device-coherent point).
// asm operands must be ext_vector types (struct uint4 inputs are rejected).
__device__ __forceinline__ u32x4 ld128_coh(const void* p) {
  u32x4 r;
  asm volatile("global_load_dwordx4 %0, %1, off sc0 sc1" : "=v"(r) : "v"(p));
  return r;
}
// "memory" clobber: later plain stores must NOT hoist above this (vmcnt(8) counts on it).
__device__ __forceinline__ void st128_coh(void* p, u32x4 v) {
  asm volatile("global_store_dwordx4 %0, %1, off sc0 sc1" :: "v"(p), "v"(v) : "memory");
}

// ushort offset of logical granule (row, seg) in a [rows][16 segs] swizzled tile.
__device__ __forceinline__ int foff(int row, int seg) {
  return (row << 7) + ((((seg & 8) | ((seg ^ row) & 7))) << 3);
}

// ---------------- prep kernels ----------------

__global__ void prep_w(const float* __restrict__ Wk, const float* __restrict__ Wr,
                       const float* __restrict__ bias,
                       unsigned short* __restrict__ Wx, unsigned short* __restrict__ Wh,
                       float* __restrict__ biasr, unsigned int* __restrict__ cnt)
{
  int gid = (blockIdx.x << 8) + threadIdx.x;   // 0 .. 2M-1
  int k   = gid >> 11;                         // 0..1023
  int col = gid & 2047;                        // original column g*512+h
  float v = (k < 512) ? Wk[((size_t)k << 11) + col]
                      : Wr[((size_t)(k - 512) << 11) + col];
  int n = ((col & 511) << 2) | (col >> 9);     // 4h+g
  if (k < 512) Wx[((size_t)n << 9) + k]         = f2bf(v);
  else         Wh[((size_t)n << 9) + (k - 512)] = f2bf(v);
  if (gid < 2048) biasr[((gid & 511) << 2) | (gid >> 9)] = bias[gid];
  if (gid < 4096) cnt[gid] = 0u;               // zero producer counters each run
}

__global__ void prep_x(const float* __restrict__ x, unsigned short* __restrict__ Xbf)
{
  int flat = (blockIdx.x << 8) + threadIdx.x;  // 0 .. 4,194,303 (granules of 8)
  int d8 = flat & 63;
  int b  = (flat >> 6) & 1023;
  int t  = flat >> 16;
  const float* src = x + ((((size_t)b << 6) + t) << 9) + (d8 << 3);
  float4 v0 = *(const float4*)src;
  float4 v1 = *(const float4*)(src + 4);
  uint4 u;
  u.x = f2bf(v0.x) | ((unsigned)f2bf(v0.y) << 16);
  u.y = f2bf(v0.z) | ((unsigned)f2bf(v0.w) << 16);
  u.z = f2bf(v1.x) | ((unsigned)f2bf(v1.y) << 16);
  u.w = f2bf(v1.z) | ((unsigned)f2bf(v1.w) << 16);
  *(uint4*)&Xbf[((((size_t)t << 10) + b) << 9) + (d8 << 3)] = u;
}

// ---------------- zx precompute GEMM ----------------
// zx[t][b][n] (fp16) = Xbf[t][b][:] . Wx[n][:]   M=65536, N=2048, K=512
__global__ __launch_bounds__(256, 3)
void zx_gemm(const unsigned short* __restrict__ Xbf, const unsigned short* __restrict__ Wx,
             unsigned short* __restrict__ zx)
{
  __shared__ __align__(16) unsigned short As[8192];   // 16 KB, 1024 granules (swizzled)
  __shared__ __align__(16) unsigned short Bs[8192];
  __shared__ float Zs[64][68];

  const int tid  = threadIdx.x;
  const int lane = tid & 63;
  const int w    = tid >> 6;
  const int llo  = lane & 15;
  const int lhi  = lane >> 4;
  const int wm   = (w >> 1) & 1;
  const int wn   = w & 1;

  const int n0 = blockIdx.x << 6;              // 0..2047 step 64
  const int by = blockIdx.y;                   // 0..1023
  const int t  = by >> 4;
  const int b0 = (by & 15) << 6;

  facc4 acc00 = {0.f,0.f,0.f,0.f};
  facc4 acc01 = acc00, acc10 = acc00, acc11 = acc00;

  const int am0 = (wm << 5) + llo;
  const int bn0 = (wn << 5) + llo;

  for (int ci = 0; ci < 4; ++ci) {
    const int kb = ci << 7;
#pragma unroll
    for (int j = 0; j < 4; ++j) {
      int p = (j << 8) + tid;
      int r = p >> 4, ps = p & 15;
      int s = (ps & 8) | ((ps ^ r) & 7);
      gl2lds16(Xbf + ((((size_t)t << 10) + (b0 + r)) << 9) + kb + (s << 3), &As[p << 3]);
      gl2lds16(Wx  + (((size_t)(n0 + r)) << 9) + kb + (s << 3),             &Bs[p << 3]);
    }
    __syncthreads();
#pragma unroll
    for (int kk = 0; kk < 4; ++kk) {
      const int s0 = (kk << 2) + lhi;
      bfrag8 a0 = *(const bfrag8*)&As[foff(am0,      s0)];
      bfrag8 a1 = *(const bfrag8*)&As[foff(am0 + 16, s0)];
      bfrag8 b0 = *(const bfrag8*)&Bs[foff(bn0,      s0)];
      bfrag8 b1 = *(const bfrag8*)&Bs[foff(bn0 + 16, s0)];
      acc00 = MFMA_B16(a0, b0, acc00);
      acc01 = MFMA_B16(a0, b1, acc01);
      acc10 = MFMA_B16(a1, b0, acc10);
      acc11 = MFMA_B16(a1, b1, acc11);
    }
    __syncthreads();
  }

  // spill: C/D layout col=lane&15, row=(lane>>4)*4+reg
#pragma unroll
  for (int rr = 0; rr < 4; ++rr) {
    int rbase = (wm << 5) + (lhi << 2) + rr;
    int cbase = (wn << 5) + llo;
    Zs[rbase][cbase]           = acc00[rr];
    Zs[rbase][cbase + 16]      = acc01[rr];
    Zs[rbase + 16][cbase]      = acc10[rr];
    Zs[rbase + 16][cbase + 16] = acc11[rr];
  }
  __syncthreads();

  const int hs = tid & 15;
  const int rw = tid >> 4;
#pragma unroll
  for (int it = 0; it < 4; ++it) {
    int row = rw + (it << 4);
    float4 z = *(const float4*)&Zs[row][hs << 2];
    ushort4 o;
    o.x = __half_as_ushort(__float2half(z.x));
    o.y = __half_as_ushort(__float2half(z.y));
    o.z = __half_as_ushort(__float2half(z.z));
    o.w = __half_as_ushort(__float2half(z.w));
    *(ushort4*)&zx[((((size_t)t << 10) + (b0 + row)) << 11) + n0 + (hs << 2)] = o;
  }
}

// ---------------- persistent recurrence v5 (producer-flag dataflow) ----------------
// 256 blocks = 16 mg (64 rows) x 16 nb (128 gate cols = 32 h), 256 thr, 1 block/CU.
// LDS (dynamic 148 KB): Bs = Wh slice [4 chunks][128 n][128 k] swizzled, RESIDENT;
//                       As = h chunk [64 b][128 k] swizzled; Sc = 4 KB h-repack scratch.
// Hstage ring: [4][16 nb][1024 b][32 h] bf16. cnt[64][16 mg][4 cg] producer counters.
__global__ __launch_bounds__(256, 1)
void lstm_persist(unsigned short* __restrict__ Hbuf,      // [4][16][1024][32] bf16 stage ring
                  const unsigned short* __restrict__ Wh,  // [2048][512] bf16
                  const unsigned short* __restrict__ zx,  // [64][1024][2048] fp16
                  const float* __restrict__ biasr,
                  float* __restrict__ out,                // [1024][64][512]
                  unsigned int* __restrict__ cnt)         // [64][16][4] producer counters
{
  extern __shared__ __align__(16) char smem_raw[];
  unsigned short* Bs = (unsigned short*)smem_raw;             // 128 KB
  unsigned short* As = (unsigned short*)(smem_raw + 131072);  // 16 KB
  unsigned short* Sc = (unsigned short*)(smem_raw + 147456);  // 4 KB

  const int tid  = threadIdx.x;
  const int lane = tid & 63;
  const int w    = tid >> 6;        // wave 0..3
  const int llo  = lane & 15;
  const int lhi  = lane >> 4;

  const int bx  = blockIdx.x;
  const int nbI = bx & 15;          // n-slice 0..15
  const int mg  = bx >> 4;          // m-group 0..15
  const int m0  = mg << 6;          // batch-row base
  const int n0  = nbI << 7;         // gate-col base (128 cols)
  const int hb  = nbI << 5;         // h base (32 h)

  // ---- prologue: stage resident Wh slice [n0..n0+128) x [0..512) into Bs ----
  for (int i = 0; i < 32; ++i) {
    int p  = (i << 8) + tid;        // 0..8191 granules of 16B
    int ci = p >> 11;               // K-chunk 0..3
    int q  = p & 2047;
    int r  = q >> 4, ps = q & 15;   // n-row 0..127, seg
    int s  = (ps & 8) | ((ps ^ r) & 7);
    gl2lds16(Wh + (((size_t)(n0 + r)) << 9) + (ci << 7) + (s << 3), Bs + ((size_t)p << 3));
  }

  const int nw0 = w << 5;           // wave's n-strip base within 128
  // bias (t-invariant): bb[nt] = biasr[4h .. 4h+3] for h = hb + w*8 + nt*4 + lhi
  float4 bb[2];
  bb[0] = *(const float4*)&biasr[(size_t)(hb + (w << 3) + 0 + lhi) << 2];
  bb[1] = *(const float4*)&biasr[(size_t)(hb + (w << 3) + 4 + lhi) << 2];

  float c[2][4] = {{0.f,0.f,0.f,0.f},{0.f,0.f,0.f,0.f}};

  asm volatile("s_waitcnt vmcnt(0)" ::: "memory");   // Bs staged
  __syncthreads();

  const size_t HSTG = (size_t)16 * 1024 * 32;        // elems per stage buffer (1 MiB)

  for (int t = 0; t < 64; ++t) {
    const unsigned short* zxt = zx + ((size_t)t << 21);

    // zx prefetch (h-independent; latency hides under flag wait + h loads)
    ushort4 zp[2][4];
#pragma unroll
    for (int nt = 0; nt < 2; ++nt)
#pragma unroll
      for (int bt = 0; bt < 4; ++bt) {
        int b = m0 + (bt << 4) + llo;
        int h = hb + (w << 3) + (nt << 2) + lhi;
        zp[nt][bt] = *(const ushort4*)&zxt[((size_t)b << 11) + (h << 2)];
      }

    facc4 acc[2][4];
#pragma unroll
    for (int nt = 0; nt < 2; ++nt)
#pragma unroll
      for (int bt = 0; bt < 4; ++bt)
        acc[nt][bt] = (facc4){0.f, 0.f, 0.f, 0.f};

    if (t) {
      // wait for the 4 producer groups of step t (threads 0-3 poll concurrently)
      if (tid < 4) {
        const unsigned int* cp = cnt + (t << 6) + (mg << 2) + tid;
        while (__hip_atomic_load(cp, __ATOMIC_RELAXED, __HIP_MEMORY_SCOPE_AGENT) < 4u)
          __builtin_amdgcn_s_sleep(1);
      }
      __syncthreads();   // all threads see the go; also fences zp loads above asm region

      const unsigned short* Hs = Hbuf + (size_t)(t & 3) * HSTG;   // ring slot for h_{t-1}
      // single-shot coherent h load: 16 x dwordx4 (64 KB/block), counted vmcnt.
      // Granule (row r, k-seg s) lives at Hstage[nbp=4ci+(s>>2)][m0+r][(s&3)*8].
      u32x4 av[16];
#pragma unroll
      for (int ci = 0; ci < 4; ++ci)
#pragma unroll
        for (int j = 0; j < 4; ++j) {
          int p = (j << 8) + tid;
          int r = p >> 4, ps = p & 15;
          int s = (ps & 8) | ((ps ^ r) & 7);
          int nbp = (ci << 2) + (s >> 2);
          av[(ci << 2) + j] =
              ld128_coh(Hs + ((size_t)nbp << 15) + ((size_t)(m0 + r) << 5) + ((s & 3) << 3));
        }
#pragma unroll
      for (int ci = 0; ci < 4; ++ci) {
        // in-order vmcnt retirement: older zp loads drain first, counts stay valid
        if      (ci == 0) asm volatile("s_waitcnt vmcnt(12)" ::: "memory");
        else if (ci == 1) asm volatile("s_waitcnt vmcnt(8)"  ::: "memory");
        else if (ci == 2) asm volatile("s_waitcnt vmcnt(4)"  ::: "memory");
        else              asm volatile("s_waitcnt vmcnt(0)"  ::: "memory");
        __builtin_amdgcn_sched_barrier(0);
#pragma unroll
        for (int j = 0; j < 4; ++j) {
          int p = (j << 8) + tid;
          *(u32x4*)&As[(size_t)p << 3] = av[(ci << 2) + j];
        }
        __syncthreads();
#pragma unroll
        for (int kk = 0; kk < 4; ++kk) {
          const int s0 = (kk << 2) + lhi;
          bfrag8 wh0 = *(const bfrag8*)&Bs[(ci << 14) + foff(nw0 + llo,      s0)];
          bfrag8 wh1 = *(const bfrag8*)&Bs[(ci << 14) + foff(nw0 + 16 + llo, s0)];
#pragma unroll
          for (int bt = 0; bt < 4; ++bt) {
            bfrag8 hf = *(const bfrag8*)&As[foff((bt << 4) + llo, s0)];
            acc[0][bt] = MFMA_B16(wh0, hf, acc[0][bt]);
            acc[1][bt] = MFMA_B16(wh1, hf, acc[1][bt]);
          }
        }
        __syncthreads();
      }
    }

    // ---- in-register epilogue: lane holds (zi,zf,zg,zo) for (h,b) ----
    float hn_s[2][4];
#pragma unroll
    for (int nt = 0; nt < 2; ++nt)
#pragma unroll
      for (int bt = 0; bt < 4; ++bt) {
        float zi = acc[nt][bt][0] + __half2float(__ushort_as_half(zp[nt][bt].x)) + bb[nt].x;
        float zf = acc[nt][bt][1] + __half2float(__ushort_as_half(zp[nt][bt].y)) + bb[nt].y;
        float zg = acc[nt][bt][2] + __half2float(__ushort_as_half(zp[nt][bt].z)) + bb[nt].z;
        float zo = acc[nt][bt][3] + __half2float(__ushort_as_half(zp[nt][bt].w)) + bb[nt].w;
        float ig = sigm(zi);
        float fg = sigm(zf);
        float gg = tanh_(zg);
        float og = sigm(zo);
        float cn = fg * c[nt][bt] + ig * gg;
        c[nt][bt] = cn;
        float hn = og * tanh_(cn);
        hn_s[nt][bt] = hn;
        // repack h via LDS scratch: Sc[wave][64 rows][8 h-of-wave]
        Sc[(w << 9) + (((bt << 4) + llo) << 3) + (nt << 2) + lhi] = f2bf(hn);
      }
    __syncthreads();   // Sc reader crosses wave regions

    // 1) stage store FIRST (one coalesced 16B per thread into block's 4 KB ring region)
    if (t < 63) {
      u32x4 hv = *(const u32x4*)&Sc[((tid & 3) << 9) + ((tid >> 2) << 3)];
      unsigned short* Hn = Hbuf + (size_t)((t + 1) & 3) * HSTG;
      st128_coh(Hn + ((size_t)nbI << 15) + ((size_t)(m0 + (tid >> 2)) << 5) + ((tid & 3) << 3), hv);
    }
    // 2) out stores (8 x 4B; merged to full lines in L2)
#pragma unroll
    for (int nt = 0; nt < 2; ++nt)
#pragma unroll
      for (int bt = 0; bt < 4; ++bt) {
        int b = m0 + (bt << 4) + llo;
        int h = hb + (w << 3) + (nt << 2) + lhi;
        out[((size_t)b << 15) + ((size_t)t << 9) + h] = hn_s[nt][bt];
      }
    // 3) drain own stage store (8 out-stores may remain in flight), sync, signal
    if (t < 63) {
      if (t == 0) asm volatile("s_waitcnt vmcnt(0)" ::: "memory");
      else        asm volatile("s_waitcnt vmcnt(8)" ::: "memory");
      __syncthreads();   // ALL threads' stage stores drained
      if (tid == 0)
        __hip_atomic_fetch_add(&cnt[((t + 1) << 6) + (mg << 2) + (nbI >> 2)], 1u,
                               __ATOMIC_RELAXED, __HIP_MEMORY_SCOPE_AGENT);
    }
  }
}

extern "C" void kernel_launch(void* const* d_in, const int* in_sizes, int n_in,
                              void* d_out, int out_size, void* d_ws, size_t ws_size,
                              hipStream_t stream) {
  const float* x    = (const float*)d_in[0];   // [1024][64][512]
  const float* Wk   = (const float*)d_in[1];   // [512][2048]
  const float* Wr   = (const float*)d_in[2];   // [512][2048]
  const float* bias = (const float*)d_in[3];   // [2048]
  float* out = (float*)d_out;                  // [1024][64][512]

  char* ws = (char*)d_ws;
  // ws: Wx@0 2MiB | Wh@2MiB 2MiB | biasr@4MiB 8KB | cnt@4MiB+8KB 16KB |
  //     Hbuf@5MiB 4MiB (ring) | Xbf@9MiB 64MiB | zx@73MiB 256MiB
  unsigned short* Wx    = (unsigned short*)(ws);
  unsigned short* Wh    = (unsigned short*)(ws + (2u << 20));
  float*          biasr = (float*)(ws + (4u << 20));
  unsigned int*   cnt   = (unsigned int*)(ws + (4u << 20) + 8192);
  unsigned short* Hbuf  = (unsigned short*)(ws + (5u << 20));
  unsigned short* Xbf   = (unsigned short*)(ws + (9u << 20));
  unsigned short* zx    = (unsigned short*)(ws + (73u << 20));

  (void)hipFuncSetAttribute((const void*)lstm_persist,
                            hipFuncAttributeMaxDynamicSharedMemorySize, 151552);

  prep_w<<<dim3(8192), dim3(256), 0, stream>>>(Wk, Wr, bias, Wx, Wh, biasr, cnt);
  prep_x<<<dim3(16384), dim3(256), 0, stream>>>(x, Xbf);
  zx_gemm<<<dim3(32, 1024), dim3(256), 0, stream>>>(Xbf, Wx, zx);
  lstm_persist<<<dim3(256), dim3(256), 151552, stream>>>(Hbuf, Wh, zx, biasr, out, cnt);
}

// Round 10
// 1147.220 us; speedup vs baseline: 1.1995x; 1.0143x over previous
//
#include <hip/hip_runtime.h>
#include <hip/hip_bf16.h>
#include <hip/hip_fp16.h>

// LSTM, T=64. Structure:
//   prep_w : Wx[2048][512], Wh[2048][512] bf16 (gate-interleaved n=4h+g, K-transposed), biasr.
//            Also zeroes the 4096 producer counters.
//   prep_x : Xbf[t][b][512] bf16 (time-major).
//   zx_gemm: zx[t][b][2048] = Xbf @ Wx^T, fp16 storage (parallel, off the critical path).
//   lstm_persist v6: 256 blocks = 16 mg (64 batch rows) x 16 nb (128 gate cols = 32 h),
//            1 block/CU, 64 steps, producer-flag dataflow (4-deep ring, per-chunk counters).
//            NEW in v6: FRAGMENT-MAJOR h stage layout Hstage[slot][mg][kseg 64][b 64][8] +
//            wave remap to (own 16-b slice) x (all 128 n). Each lane's coherent 16B load IS
//            an MFMA B-fragment (lane llo->b, lhi->k-subseg) -> As LDS staging and ALL
//            GEMM-phase __syncthreads eliminated (3 barriers/step total). Waves fully
//            independent through load+MFMA; Bs (Wh) is read-only shared.
//            Wh LDS-RESIDENT; lane's facc4 = (zi,zf,zg,zo) for one (h',b); c in registers.
// LDS swizzle (Bs): phys granule = (seg&8)|((seg^row)&7) -> bank-optimal frag reads.

typedef __attribute__((ext_vector_type(8))) short bfrag8;
typedef __attribute__((ext_vector_type(4))) float facc4;
typedef __attribute__((ext_vector_type(4))) unsigned int u32x4;  // asm-friendly 128b

#define MFMA_B16(a, b, c) __builtin_amdgcn_mfma_f32_16x16x32_bf16(a, b, c, 0, 0, 0)

__device__ __forceinline__ unsigned short f2bf(float f) {
  unsigned int u = __float_as_uint(f);
  u += 0x7FFFu + ((u >> 16) & 1u);          // RNE
  return (unsigned short)(u >> 16);
}
__device__ __forceinline__ float sigm(float x)  { return 1.0f / (1.0f + __expf(-x)); }
__device__ __forceinline__ float tanh_(float x) { return 1.0f - 2.0f / (__expf(2.0f * x) + 1.0f); }

__device__ __forceinline__ void gl2lds16(const void* g, void* l) {
  __builtin_amdgcn_global_load_lds(
      (const __attribute__((address_space(1))) unsigned int*)g,
      (__attribute__((address_space(3))) unsigned int*)l, 16, 0, 0);
}

// Coherent 16B load/store (bypass stale L1/L2, device-coherent point).
__device__ __forceinline__ u32x4 ld128_coh(const void* p) {
  u32x4 r;
  asm volatile("global_load_dwordx4 %0, %1, off sc0 sc1" : "=v"(r) : "v"(p));
  return r;
}
__device__ __forceinline__ void st128_coh(void* p, u32x4 v) {
  asm volatile("global_store_dwordx4 %0, %1, off sc0 sc1" :: "v"(p), "v"(v) : "memory");
}

// ushort offset of logical granule (row, seg) in a [rows][16 segs] swizzled tile.
__device__ __forceinline__ int foff(int row, int seg) {
  return (row << 7) + ((((seg & 8) | ((seg ^ row) & 7))) << 3);
}

// ---------------- prep kernels ----------------

__global__ void prep_w(const float* __restrict__ Wk, const float* __restrict__ Wr,
                       const float* __restrict__ bias,
                       unsigned short* __restrict__ Wx, unsigned short* __restrict__ Wh,
                       float* __restrict__ biasr, unsigned int* __restrict__ cnt)
{
  int gid = (blockIdx.x << 8) + threadIdx.x;   // 0 .. 2M-1
  int k   = gid >> 11;                         // 0..1023
  int col = gid & 2047;                        // original column g*512+h
  float v = (k < 512) ? Wk[((size_t)k << 11) + col]
                      : Wr[((size_t)(k - 512) << 11) + col];
  int n = ((col & 511) << 2) | (col >> 9);     // 4h+g
  if (k < 512) Wx[((size_t)n << 9) + k]         = f2bf(v);
  else         Wh[((size_t)n << 9) + (k - 512)] = f2bf(v);
  if (gid < 2048) biasr[((gid & 511) << 2) | (gid >> 9)] = bias[gid];
  if (gid < 4096) cnt[gid] = 0u;               // zero producer counters each run
}

__global__ void prep_x(const float* __restrict__ x, unsigned short* __restrict__ Xbf)
{
  int flat = (blockIdx.x << 8) + threadIdx.x;  // 0 .. 4,194,303 (granules of 8)
  int d8 = flat & 63;
  int b  = (flat >> 6) & 1023;
  int t  = flat >> 16;
  const float* src = x + ((((size_t)b << 6) + t) << 9) + (d8 << 3);
  float4 v0 = *(const float4*)src;
  float4 v1 = *(const float4*)(src + 4);
  uint4 u;
  u.x = f2bf(v0.x) | ((unsigned)f2bf(v0.y) << 16);
  u.y = f2bf(v0.z) | ((unsigned)f2bf(v0.w) << 16);
  u.z = f2bf(v1.x) | ((unsigned)f2bf(v1.y) << 16);
  u.w = f2bf(v1.z) | ((unsigned)f2bf(v1.w) << 16);
  *(uint4*)&Xbf[((((size_t)t << 10) + b) << 9) + (d8 << 3)] = u;
}

// ---------------- zx precompute GEMM ----------------
// zx[t][b][n] (fp16) = Xbf[t][b][:] . Wx[n][:]   M=65536, N=2048, K=512
__global__ __launch_bounds__(256, 3)
void zx_gemm(const unsigned short* __restrict__ Xbf, const unsigned short* __restrict__ Wx,
             unsigned short* __restrict__ zx)
{
  __shared__ __align__(16) unsigned short As[8192];   // 16 KB, 1024 granules (swizzled)
  __shared__ __align__(16) unsigned short Bs[8192];
  __shared__ float Zs[64][68];

  const int tid  = threadIdx.x;
  const int lane = tid & 63;
  const int w    = tid >> 6;
  const int llo  = lane & 15;
  const int lhi  = lane >> 4;
  const int wm   = (w >> 1) & 1;
  const int wn   = w & 1;

  const int n0 = blockIdx.x << 6;              // 0..2047 step 64
  const int by = blockIdx.y;                   // 0..1023
  const int t  = by >> 4;
  const int b0 = (by & 15) << 6;

  facc4 acc00 = {0.f,0.f,0.f,0.f};
  facc4 acc01 = acc00, acc10 = acc00, acc11 = acc00;

  const int am0 = (wm << 5) + llo;
  const int bn0 = (wn << 5) + llo;

  for (int ci = 0; ci < 4; ++ci) {
    const int kb = ci << 7;
#pragma unroll
    for (int j = 0; j < 4; ++j) {
      int p = (j << 8) + tid;
      int r = p >> 4, ps = p & 15;
      int s = (ps & 8) | ((ps ^ r) & 7);
      gl2lds16(Xbf + ((((size_t)t << 10) + (b0 + r)) << 9) + kb + (s << 3), &As[p << 3]);
      gl2lds16(Wx  + (((size_t)(n0 + r)) << 9) + kb + (s << 3),             &Bs[p << 3]);
    }
    __syncthreads();
#pragma unroll
    for (int kk = 0; kk < 4; ++kk) {
      const int s0 = (kk << 2) + lhi;
      bfrag8 a0 = *(const bfrag8*)&As[foff(am0,      s0)];
      bfrag8 a1 = *(const bfrag8*)&As[foff(am0 + 16, s0)];
      bfrag8 b0 = *(const bfrag8*)&Bs[foff(bn0,      s0)];
      bfrag8 b1 = *(const bfrag8*)&Bs[foff(bn0 + 16, s0)];
      acc00 = MFMA_B16(a0, b0, acc00);
      acc01 = MFMA_B16(a0, b1, acc01);
      acc10 = MFMA_B16(a1, b0, acc10);
      acc11 = MFMA_B16(a1, b1, acc11);
    }
    __syncthreads();
  }

  // spill: C/D layout col=lane&15, row=(lane>>4)*4+reg
#pragma unroll
  for (int rr = 0; rr < 4; ++rr) {
    int rbase = (wm << 5) + (lhi << 2) + rr;
    int cbase = (wn << 5) + llo;
    Zs[rbase][cbase]           = acc00[rr];
    Zs[rbase][cbase + 16]      = acc01[rr];
    Zs[rbase + 16][cbase]      = acc10[rr];
    Zs[rbase + 16][cbase + 16] = acc11[rr];
  }
  __syncthreads();

  const int hs = tid & 15;
  const int rw = tid >> 4;
#pragma unroll
  for (int it = 0; it < 4; ++it) {
    int row = rw + (it << 4);
    float4 z = *(const float4*)&Zs[row][hs << 2];
    ushort4 o;
    o.x = __half_as_ushort(__float2half(z.x));
    o.y = __half_as_ushort(__float2half(z.y));
    o.z = __half_as_ushort(__float2half(z.z));
    o.w = __half_as_ushort(__float2half(z.w));
    *(ushort4*)&zx[((((size_t)t << 10) + (b0 + row)) << 11) + n0 + (hs << 2)] = o;
  }
}

// ---------------- persistent recurrence v6 (fragment-direct h path) ----------------
// 256 blocks = 16 mg x 16 nb, 256 thr, 1 block/CU. Wave w owns b-rows [w*16, w*16+16),
// all 128 n cols. LDS: Bs (Wh, 128 KB resident) + Sc (4 KB h-repack) + Bias (512 B).
// Hstage ring: [4][16 mg][64 kseg][64 b][8] bf16. cnt[64][16 mg][4 cg] producer counters.
__global__ __launch_bounds__(256, 1)
void lstm_persist(unsigned short* __restrict__ Hbuf,      // stage ring (4 MiB)
                  const unsigned short* __restrict__ Wh,  // [2048][512] bf16
                  const unsigned short* __restrict__ zx,  // [64][1024][2048] fp16
                  const float* __restrict__ biasr,
                  float* __restrict__ out,                // [1024][64][512]
                  unsigned int* __restrict__ cnt)         // [64][16][4] producer counters
{
  extern __shared__ __align__(16) char smem_raw[];
  unsigned short* Bs   = (unsigned short*)smem_raw;             // 128 KB
  unsigned short* Sc   = (unsigned short*)(smem_raw + 131072);  // [4 ksl][64 b][8] = 4 KB
  float*          Bias = (float*)(smem_raw + 135168);           // [32 h'][4 g] = 512 B

  const int tid  = threadIdx.x;
  const int lane = tid & 63;
  const int w    = tid >> 6;        // wave 0..3 -> b-slice
  const int llo  = lane & 15;
  const int lhi  = lane >> 4;       // 0..3

  const int bx  = blockIdx.x;
  const int nbI = bx & 15;          // n-slice 0..15
  const int mg  = bx >> 4;          // m-group 0..15
  const int m0  = mg << 6;          // batch-row base
  const int n0  = nbI << 7;         // gate-col base (128 cols)
  const int hb  = nbI << 5;         // h base (32 h)

  // ---- prologue: stage resident Wh slice [n0..n0+128) x [0..512) into Bs ----
  for (int i = 0; i < 32; ++i) {
    int p  = (i << 8) + tid;        // 0..8191 granules of 16B
    int ci = p >> 11;               // K-chunk 0..3
    int q  = p & 2047;
    int r  = q >> 4, ps = q & 15;   // n-row 0..127, seg
    int s  = (ps & 8) | ((ps ^ r) & 7);
    gl2lds16(Wh + (((size_t)(n0 + r)) << 9) + (ci << 7) + (s << 3), Bs + ((size_t)p << 3));
  }
  if (tid < 128) Bias[tid] = biasr[((size_t)hb << 2) + tid];   // 32 h' x 4 gates

  float c[8];
#pragma unroll
  for (int i = 0; i < 8; ++i) c[i] = 0.f;

  const int bmine = m0 + (w << 4) + llo;   // this lane's batch row

  asm volatile("s_waitcnt vmcnt(0)" ::: "memory");   // Bs staged
  __syncthreads();                                    // also covers Bias

  const size_t HSTG = (size_t)16 * 64 * 64 * 8;      // elems per ring slot (1 MiB)

  for (int t = 0; t < 64; ++t) {
    const unsigned short* zxt = zx + ((size_t)t << 21);

    // zx prefetch: 8 x 16B per lane (own b-row, all 8 h'-quads of this slice)
    ushort4 zp[8];
#pragma unroll
    for (int nt = 0; nt < 8; ++nt)
      zp[nt] = *(const ushort4*)&zxt[((size_t)bmine << 11) + ((hb + (nt << 2) + lhi) << 2)];

    facc4 acc[8];
#pragma unroll
    for (int nt = 0; nt < 8; ++nt) acc[nt] = (facc4){0.f, 0.f, 0.f, 0.f};

    if (t) {
      // wait for the 4 producer groups of step t (threads 0-3 poll concurrently)
      if (tid < 4) {
        const unsigned int* cp = cnt + (t << 6) + (mg << 2) + tid;
        while (__hip_atomic_load(cp, __ATOMIC_RELAXED, __HIP_MEMORY_SCOPE_AGENT) < 4u)
          __builtin_amdgcn_s_sleep(1);
      }
      __syncthreads();

      const unsigned short* Hs = Hbuf + (size_t)(t & 3) * HSTG + ((size_t)mg << 15);

      // fragment-direct coherent loads: av[ci*4+j] IS the B-fragment for (ci, kk=j).
      // addr: [kseg = ci*16 + j*4 + lhi][b = w*16 + llo] -> 256B-contiguous per lhi-group.
      u32x4 av[16];
#pragma unroll
      for (int ci = 0; ci < 4; ++ci)
#pragma unroll
        for (int j = 0; j < 4; ++j) {
          int kseg = (ci << 4) + (j << 2) + lhi;
          av[(ci << 2) + j] = ld128_coh(Hs + (((kseg << 6) + (w << 4) + llo) << 3));
        }
      // counted vmcnt covers worst-case stragglers: 8 prev-step out-stores + 8 zp loads.
#pragma unroll
      for (int ci = 0; ci < 4; ++ci) {
        if      (ci == 0) asm volatile("s_waitcnt vmcnt(12)" ::: "memory");
        else if (ci == 1) asm volatile("s_waitcnt vmcnt(8)"  ::: "memory");
        else if (ci == 2) asm volatile("s_waitcnt vmcnt(4)"  ::: "memory");
        else              asm volatile("s_waitcnt vmcnt(0)"  ::: "memory");
        __builtin_amdgcn_sched_barrier(0);
#pragma unroll
        for (int kk = 0; kk < 4; ++kk) {
          bfrag8 hf = __builtin_bit_cast(bfrag8, av[(ci << 2) + kk]);
          const int s0 = (kk << 2) + lhi;
#pragma unroll
          for (int nt = 0; nt < 8; ++nt) {
            bfrag8 wh = *(const bfrag8*)&Bs[(ci << 14) + foff((nt << 4) + llo, s0)];
            acc[nt] = MFMA_B16(wh, hf, acc[nt]);
          }
        }
      }
    }

    // ---- in-register epilogue: lane holds (zi,zf,zg,zo) for (h' = nt*4+lhi, b = bmine) ----
    float hn_s[8];
#pragma unroll
    for (int nt = 0; nt < 8; ++nt) {
      float4 bbv = *(const float4*)&Bias[((nt << 2) + lhi) << 2];
      float zi = acc[nt][0] + __half2float(__ushort_as_half(zp[nt].x)) + bbv.x;
      float zf = acc[nt][1] + __half2float(__ushort_as_half(zp[nt].y)) + bbv.y;
      float zg = acc[nt][2] + __half2float(__ushort_as_half(zp[nt].z)) + bbv.z;
      float zo = acc[nt][3] + __half2float(__ushort_as_half(zp[nt].w)) + bbv.w;
      float ig = sigm(zi);
      float fg = sigm(zf);
      float gg = tanh_(zg);
      float og = sigm(zo);
      float cn = fg * c[nt] + ig * gg;
      c[nt] = cn;
      float hn = og * tanh_(cn);
      hn_s[nt] = hn;
      // repack to stage layout: Sc[ksl = nt>>1][b local][e = (nt&1)*4 + lhi]
      Sc[((nt >> 1) << 9) + (((w << 4) + llo) << 3) + ((nt & 1) << 2) + lhi] = f2bf(hn);
    }
    __syncthreads();   // Sc complete (readers cross wave regions)

    // 1) stage store FIRST: thread tid -> 16B granule (ksl = tid>>6, b = tid&63)
    if (t < 63) {
      u32x4 hv = *(const u32x4*)&Sc[((tid >> 6) << 9) + ((tid & 63) << 3)];
      unsigned short* Hn = Hbuf + (size_t)((t + 1) & 3) * HSTG + ((size_t)mg << 15);
      st128_coh(Hn + (((((nbI << 2) + (tid >> 6)) << 6) + (tid & 63)) << 3), hv);
    }
    // 2) out stores (8 x 4B; L2 write-combines within the wave's epilogue burst)
#pragma unroll
    for (int nt = 0; nt < 8; ++nt)
      out[((size_t)bmine << 15) + ((size_t)t << 9) + hb + (nt << 2) + lhi] = hn_s[nt];
    // 3) drain own stage store (out stores may stay in flight), sync, signal
    if (t < 63) {
      if (t == 0) asm volatile("s_waitcnt vmcnt(0)" ::: "memory");
      else        asm volatile("s_waitcnt vmcnt(8)" ::: "memory");
      __syncthreads();   // ALL threads' stage stores drained; also Sc reuse fence
      if (tid == 0)
        __hip_atomic_fetch_add(&cnt[((t + 1) << 6) + (mg << 2) + (nbI >> 2)], 1u,
                               __ATOMIC_RELAXED, __HIP_MEMORY_SCOPE_AGENT);
    }
  }
}

extern "C" void kernel_launch(void* const* d_in, const int* in_sizes, int n_in,
                              void* d_out, int out_size, void* d_ws, size_t ws_size,
                              hipStream_t stream) {
  const float* x    = (const float*)d_in[0];   // [1024][64][512]
  const float* Wk   = (const float*)d_in[1];   // [512][2048]
  const float* Wr   = (const float*)d_in[2];   // [512][2048]
  const float* bias = (const float*)d_in[3];   // [2048]
  float* out = (float*)d_out;                  // [1024][64][512]

  char* ws = (char*)d_ws;
  // ws: Wx@0 2MiB | Wh@2MiB 2MiB | biasr@4MiB 8KB | cnt@4MiB+8KB 16KB |
  //     Hbuf@5MiB 4MiB (ring) | Xbf@9MiB 64MiB | zx@73MiB 256MiB
  unsigned short* Wx    = (unsigned short*)(ws);
  unsigned short* Wh    = (unsigned short*)(ws + (2u << 20));
  float*          biasr = (float*)(ws + (4u << 20));
  unsigned int*   cnt   = (unsigned int*)(ws + (4u << 20) + 8192);
  unsigned short* Hbuf  = (unsigned short*)(ws + (5u << 20));
  unsigned short* Xbf   = (unsigned short*)(ws + (9u << 20));
  unsigned short* zx    = (unsigned short*)(ws + (73u << 20));

  (void)hipFuncSetAttribute((const void*)lstm_persist,
                            hipFuncAttributeMaxDynamicSharedMemorySize, 135680);

  prep_w<<<dim3(8192), dim3(256), 0, stream>>>(Wk, Wr, bias, Wx, Wh, biasr, cnt);
  prep_x<<<dim3(16384), dim3(256), 0, stream>>>(x, Xbf);
  zx_gemm<<<dim3(32, 1024), dim3(256), 0, stream>>>(Xbf, Wx, zx);
  lstm_persist<<<dim3(256), dim3(256), 135680, stream>>>(Hbuf, Wh, zx, biasr, out, cnt);
}